// Round 10
// baseline (162.744 us; speedup 1.0000x reference)
//
#include <hip/hip_runtime.h>
#include <stdint.h>

#define IN_DIM 128
#define NCOL   256   // UV row: [U(128) | V(128)], bf16
#define CHUNK_B (32 * IN_DIM * 4)   // one A-chunk in LDS: 16 KB

typedef __bf16 bfx8 __attribute__((ext_vector_type(8)));
typedef __bf16 bfx4 __attribute__((ext_vector_type(4)));
typedef float  f32x4 __attribute__((ext_vector_type(4)));
typedef __attribute__((address_space(3))) void lds_void;

// XOR-swizzle on chunk-local byte offsets (16 KB = 32 rows x 512 B).
// Involution; keeps 16B alignment; applied on BOTH sides (pre-swizzled
// global source for linear-dest global_load_lds + swizzled ds_read).
__device__ __forceinline__ int swz(int x) { return x ^ (((x >> 9) & 7) << 4); }

// ---------------- GEMM: UV = bf16( z @ Weff^T + [b1|0] ) ----------------
// R10: occupancy was never actually raised — the 64 KB ring capped residency
// at 2 blocks/CU (160/64) and rf[2][4][2] (~190 VGPR) at 2 waves/SIMD.
// This version: 3 x 16 KB ring (48 KB -> 3 blocks/CU), prefetch depth 2,
// per-kk alternating 16-reg read windows with counted lgkmcnt(4) (live rf
// 64 -> 32, natural VGPR ~150), launch_bounds(256,3) (cap 170), grid 768
// (= exactly 3 blocks/CU of supply).
// vmcnt accounting (per wave, [4 loads][8 stores] per iter, prologue = 2x4
// loads): iter0 wait 8, iter1 16, steady 24, i==T-2 20, i==T-1 16.
// Over-wait is always safe (vmcnt(N) = drain to <=N outstanding).
// Ring-3 hazard: iter i stages buf (i+2)%3 = buf consumed at iter i-1;
// its ds_reads completed before barrier2(i-1) (lgkmcnt(0) precedes it),
// and the STAGE is issued after barrier2(i-1) -> no overlap.
__global__ __launch_bounds__(256, 3) void gemm_mfma(
    const float* __restrict__ z, const float* __restrict__ W1,
    const float* __restrict__ b1, __bf16* __restrict__ UV, int nchunks)
{
    __shared__ float abuf[3][32 * IN_DIM];   // 3 x 16 KB ring

    const int tid  = threadIdx.x;
    const int wave = tid >> 6;
    const int lane = tid & 63;
    const int l15  = lane & 15;
    const int q    = lane >> 4;      // quad 0..3
    const int n0   = wave * 64;

    // --- B fragments from W1 f32 (L2/L3-hot), fused concat:
    // Weff[n][k] = (n<128) ? W1[n][k] : W1[n-128][128+k]
    bfx8  bfrag[4][4];
    f32x4 bias[4];
#pragma unroll
    for (int nt = 0; nt < 4; ++nt) {
        const int n = n0 + nt * 16 + l15;
        const float* src = (n < 128) ? (W1 + (size_t)n * 256)
                                     : (W1 + (size_t)(n - 128) * 256 + 128);
#pragma unroll
        for (int kk = 0; kk < 4; ++kk) {
            float4 f0 = *(const float4*)(src + kk * 32 + q * 8);
            float4 f1 = *(const float4*)(src + kk * 32 + q * 8 + 4);
            bfx8 b;
            b[0]=(__bf16)f0.x; b[1]=(__bf16)f0.y; b[2]=(__bf16)f0.z; b[3]=(__bf16)f0.w;
            b[4]=(__bf16)f1.x; b[5]=(__bf16)f1.y; b[6]=(__bf16)f1.z; b[7]=(__bf16)f1.w;
            bfrag[nt][kk] = b;
        }
        if (n0 + nt * 16 < 128) bias[nt] = *(const f32x4*)(b1 + n0 + nt * 16 + q * 4);
        else                    bias[nt] = (f32x4){0.f, 0.f, 0.f, 0.f};
    }

    const uint32_t lds0 = (uint32_t)(uintptr_t)(lds_void*)&abuf[0][0];

    auto STAGE = [&](int b, int cc) {
        const char* gbase = (const char*)(z + (size_t)cc * 32 * IN_DIM);
#pragma unroll
        for (int i = 0; i < 4; ++i) {
            const int seg  = (wave * 4 + i) << 10;   // 1 KB per wave-instr
            const int loff = seg + lane * 16;
            __builtin_amdgcn_global_load_lds(
                (const __attribute__((address_space(1))) void*)(gbase + swz(loff)),
                (lds_void*)((char*)&abuf[b][0] + seg),
                16, 0, 0);
        }
    };

    // grid = 768, nchunks = 3125 -> T in {4,5} (T >= 4 required by the
    // warmup/tail vmcnt constants).
    const int T = (nchunks - blockIdx.x + gridDim.x - 1) / gridDim.x;

    STAGE(0, blockIdx.x);
    STAGE(1, blockIdx.x + gridDim.x);

    int bi = 0;   // read-buffer index for iter i (== i mod 3)
    for (int i = 0; i < T; ++i) {
        const int c  = blockIdx.x + i * gridDim.x;
        const bool st = (i + 2 < T);
        int sb = bi + 2; if (sb >= 3) sb -= 3;
        if (st) STAGE(sb, c + 2 * gridDim.x);

        if      (i == 0)     asm volatile("s_waitcnt vmcnt(8)"  ::: "memory");
        else if (i == 1)     asm volatile("s_waitcnt vmcnt(16)" ::: "memory");
        else if (st)         asm volatile("s_waitcnt vmcnt(24)" ::: "memory");
        else if (i == T - 2) asm volatile("s_waitcnt vmcnt(20)" ::: "memory");
        else                 asm volatile("s_waitcnt vmcnt(16)" ::: "memory");
        __builtin_amdgcn_s_barrier();
        asm volatile("" ::: "memory");

        const uint32_t tb = lds0 + (uint32_t)(bi * CHUNK_B);

        // per-kk 4 x ds_read_b128 into an alternating 16-reg window
        auto RD = [&](f32x4 (&rf)[2][2], int kk) {
#pragma unroll
            for (int mt = 0; mt < 2; ++mt)
#pragma unroll
                for (int h = 0; h < 2; ++h) {
                    const int o = (mt * 16 + l15) * 512 + kk * 128 + q * 32 + h * 16;
                    asm volatile("ds_read_b128 %0, %1"
                                 : "=v"(rf[mt][h])
                                 : "v"(tb + (uint32_t)swz(o)));
                }
        };

        f32x4 acc[2][4];
#pragma unroll
        for (int mt = 0; mt < 2; ++mt)
#pragma unroll
            for (int nt = 0; nt < 4; ++nt)
                acc[mt][nt] = (f32x4){0.f, 0.f, 0.f, 0.f};

        auto CM = [&](f32x4 (&rf)[2][2], int kk) {
            bfx8 af[2];
#pragma unroll
            for (int mt = 0; mt < 2; ++mt) {
                f32x4 f0 = rf[mt][0], f1 = rf[mt][1];
                bfx8 a;
                a[0]=(__bf16)f0[0]; a[1]=(__bf16)f0[1]; a[2]=(__bf16)f0[2]; a[3]=(__bf16)f0[3];
                a[4]=(__bf16)f1[0]; a[5]=(__bf16)f1[1]; a[6]=(__bf16)f1[2]; a[7]=(__bf16)f1[3];
                af[mt] = a;
            }
#pragma unroll
            for (int mt = 0; mt < 2; ++mt)
#pragma unroll
                for (int nt = 0; nt < 4; ++nt)
                    acc[mt][nt] = __builtin_amdgcn_mfma_f32_16x16x32_bf16(
                        bfrag[nt][kk], af[mt], acc[mt][nt], 0, 0, 0);
        };

        f32x4 rfA[2][2], rfB[2][2];
        RD(rfA, 0);
        RD(rfB, 1);
        asm volatile("s_waitcnt lgkmcnt(4)" ::: "memory");   // rfA (kk=0) done
        __builtin_amdgcn_sched_barrier(0);                   // rule #18
        CM(rfA, 0);
        RD(rfA, 2);
        asm volatile("s_waitcnt lgkmcnt(4)" ::: "memory");   // rfB (kk=1) done
        __builtin_amdgcn_sched_barrier(0);
        CM(rfB, 1);
        RD(rfB, 3);
        asm volatile("s_waitcnt lgkmcnt(4)" ::: "memory");   // rfA (kk=2) done
        __builtin_amdgcn_sched_barrier(0);
        CM(rfA, 2);
        asm volatile("s_waitcnt lgkmcnt(0)" ::: "memory");   // rfB (kk=3) done
        __builtin_amdgcn_sched_barrier(0);
        CM(rfB, 3);

        // --- direct epilogue: lane owns row m0+mt*16+l15, cols n0+nt*16+q*4..+4
        // (exactly 8 x 8B stores per wave -> the vmcnt N constants above) ---
        const int m0 = c * 32;
#pragma unroll
        for (int mt = 0; mt < 2; ++mt) {
            __bf16* dst = UV + (size_t)(m0 + mt * 16 + l15) * NCOL + n0 + q * 4;
#pragma unroll
            for (int nt = 0; nt < 4; ++nt) {
                bfx4 v;
#pragma unroll
                for (int r = 0; r < 4; ++r)
                    v[r] = (__bf16)(acc[mt][nt][r] + bias[nt][r]);
                *(bfx4*)(dst + nt * 16) = v;
            }
        }

        asm volatile("" ::: "memory");
        __builtin_amdgcn_s_barrier();
        asm volatile("" ::: "memory");
        bi = (bi == 2) ? 0 : bi + 1;
    }
}

// ---------------- per-edge MLP (single dispatch, R5 form) ----------------
// R6: 2x gather-ILP neutral => bound by L2-miss fill (~141 MB @ ~3.4 TB/s),
// structural for random gathers over a 51 MB table. R9's two-dispatch split
// cost +4.6 us launch overhead -> reverted.
__global__ __launch_bounds__(256) void edge_mlp(
    const __bf16* __restrict__ UV, const int* __restrict__ ei,
    const float* __restrict__ W2, const float* __restrict__ b2,
    float* __restrict__ out, int E)
{
    const int gt   = blockIdx.x * blockDim.x + threadIdx.x;
    const int lane = threadIdx.x & 15;
    const int g    = gt >> 4;
    const int e0   = g * 2;
    const int j0   = lane * 8;

    float ww[8];
    {
        float4 w0 = *(const float4*)(W2 + j0);
        float4 w1 = *(const float4*)(W2 + j0 + 4);
        ww[0] = w0.x; ww[1] = w0.y; ww[2] = w0.z; ww[3] = w0.w;
        ww[4] = w1.x; ww[5] = w1.y; ww[6] = w1.z; ww[7] = w1.w;
    }

    if (e0 >= E) return;   // E is even

    const int2 srcp = *(const int2*)(ei + e0);       // src of e0, e0+1
    const int2 dstp = *(const int2*)(ei + E + e0);   // dst of e0, e0+1

    bfx8 u0 = *(const bfx8*)(UV + (size_t)srcp.x * NCOL + j0);
    bfx8 v0 = *(const bfx8*)(UV + (size_t)dstp.x * NCOL + 128 + j0);
    bfx8 u1 = *(const bfx8*)(UV + (size_t)srcp.y * NCOL + j0);
    bfx8 v1 = *(const bfx8*)(UV + (size_t)dstp.y * NCOL + 128 + j0);

    float s0 = 0.f, s1 = 0.f;
#pragma unroll
    for (int i = 0; i < 8; ++i) {
        float h0 = (float)u0[i] + (float)v0[i];
        float h1 = (float)u1[i] + (float)v1[i];
        s0 = fmaf(fmaxf(h0, 0.f), ww[i], s0);
        s1 = fmaf(fmaxf(h1, 0.f), ww[i], s1);
    }

#pragma unroll
    for (int d = 1; d < 16; d <<= 1) {
        s0 += __shfl_xor(s0, d);
        s1 += __shfl_xor(s1, d);
    }

    if (lane == 0) {
        float bb = b2[0];
        *(float2*)(out + e0) = make_float2(s0 + bb, s1 + bb);
    }
}

extern "C" void kernel_launch(void* const* d_in, const int* in_sizes, int n_in,
                              void* d_out, int out_size, void* d_ws, size_t ws_size,
                              hipStream_t stream)
{
    const float* z  = (const float*)d_in[0];
    const int*   ei = (const int*)d_in[1];
    const float* W1 = (const float*)d_in[2];
    const float* b1 = (const float*)d_in[3];
    const float* W2 = (const float*)d_in[4];
    const float* b2 = (const float*)d_in[5];
    float* out = (float*)d_out;

    const int M = in_sizes[0] / IN_DIM;   // 100000 nodes
    const int E = in_sizes[1] / 2;        // 600000 edges

    __bf16* UV = (__bf16*)d_ws;           // [M][256] bf16 = 51.2 MB

    const int nchunks = M / 32;           // 3125 (M % 32 == 0)
    gemm_mfma<<<768, 256, 0, stream>>>(z, W1, b1, UV, nchunks);

    int groups  = (E + 1) / 2;            // 2 edges per 16-lane group
    int eblocks = (groups * 16 + 255) / 256;  // 18750
    edge_mlp<<<eblocks, 256, 0, stream>>>(UV, ei, W2, b2, out, E);
}

// Round 11
// 157.217 us; speedup vs baseline: 1.0352x; 1.0352x over previous
//
#include <hip/hip_runtime.h>
#include <stdint.h>

#define IN_DIM 128
#define NCOL   256   // UV row: [U(128) | V(128)], bf16
#define CHUNK_B (32 * IN_DIM * 4)   // one A-chunk in LDS: 16 KB

typedef __bf16 bfx8 __attribute__((ext_vector_type(8)));
typedef __bf16 bfx4 __attribute__((ext_vector_type(4)));
typedef float  f32x4 __attribute__((ext_vector_type(4)));
typedef __attribute__((address_space(3))) void lds_void;

// XOR-swizzle on chunk-local byte offsets (16 KB = 32 rows x 512 B).
// Involution; keeps 16B alignment; applied on BOTH sides (pre-swizzled
// global source for linear-dest global_load_lds + swizzled ds_read).
__device__ __forceinline__ int swz(int x) { return x ^ (((x >> 9) & 7) << 4); }

// ---------------- pre-pass: Weff[n][k] = bf16 fused layer-1 weight ----------
// Weff[n][k] = (n<128) ? W1[n][k] : W1[n-128][128+k];  [256][128] bf16, 64 KB.
// R11 rationale: each gemm block re-reads its B-operand at block start. From
// f32 W1 that is 128 KB/block -> 65 MB of L3 traffic at 512 blocks, invisible
// in FETCH_SIZE (L3-resident) but real time. This model fits R4/R7/R10's
// "more blocks = slower by ~the added prologue bytes" to within 2x. bf16
// Weff halves it and deletes all prologue cvts. Cost: ~3 us serial head.
__global__ __launch_bounds__(256) void prep_w(
    const float* __restrict__ W1, __bf16* __restrict__ Weff)
{
    const int n = threadIdx.x;    // one row per thread, 256 threads
    const float* src = (n < 128) ? (W1 + n * 256) : (W1 + (n - 128) * 256 + 128);
    __bf16* dst = Weff + n * IN_DIM;
#pragma unroll
    for (int k = 0; k < IN_DIM; k += 4) {
        float4 f = *(const float4*)(src + k);
        bfx4 b;
        b[0] = (__bf16)f.x; b[1] = (__bf16)f.y; b[2] = (__bf16)f.z; b[3] = (__bf16)f.w;
        *(bfx4*)(dst + k) = b;
    }
}

// ---------------- GEMM: UV = bf16( z @ Weff^T + [b1|0] ) ----------------
// Exact R8 structure (proven best, 151.5 total): 4-buffer LDS ring, prefetch
// depth 3, raw s_barrier + counted s_waitcnt vmcnt(N); warmup 12/20/28,
// steady 36, tail 8; grid 512 (T in {6,7}, T>=6 required).
// R11 change: B-fragments load from pre-packed bf16 Weff (bfx8 direct,
// 64 KB/block) instead of f32 W1 (128 KB/block + 128 cvts).
// vmcnt safety with prologue loads: per-wave vmem retires FIFO; the counted
// waits only ever over-wait (drain prologue first) -> correct.
__global__ __launch_bounds__(256, 2) void gemm_mfma(
    const float* __restrict__ z, const __bf16* __restrict__ Weff,
    const float* __restrict__ b1, __bf16* __restrict__ UV, int nchunks)
{
    __shared__ float abuf[4][32 * IN_DIM];   // 4 x 16 KB ring

    const int tid  = threadIdx.x;
    const int wave = tid >> 6;
    const int lane = tid & 63;
    const int l15  = lane & 15;
    const int q    = lane >> 4;      // quad 0..3
    const int n0   = wave * 64;

    // --- B fragments from Weff bf16: lane holds Weff[n][kk*32+q*8 ..+8] ---
    bfx8  bfrag[4][4];
    f32x4 bias[4];
#pragma unroll
    for (int nt = 0; nt < 4; ++nt) {
        const int n = n0 + nt * 16 + l15;
        const __bf16* src = Weff + n * IN_DIM;
#pragma unroll
        for (int kk = 0; kk < 4; ++kk)
            bfrag[nt][kk] = *(const bfx8*)(src + kk * 32 + q * 8);
        if (n0 + nt * 16 < 128) bias[nt] = *(const f32x4*)(b1 + n0 + nt * 16 + q * 4);
        else                    bias[nt] = (f32x4){0.f, 0.f, 0.f, 0.f};
    }

    const uint32_t lds0 = (uint32_t)(uintptr_t)(lds_void*)&abuf[0][0];

    auto STAGE = [&](int b, int cc) {
        const char* gbase = (const char*)(z + (size_t)cc * 32 * IN_DIM);
#pragma unroll
        for (int i = 0; i < 4; ++i) {
            const int seg  = (wave * 4 + i) << 10;   // 1 KB per wave-instr
            const int loff = seg + lane * 16;
            __builtin_amdgcn_global_load_lds(
                (const __attribute__((address_space(1))) void*)(gbase + swz(loff)),
                (lds_void*)((char*)&abuf[b][0] + seg),
                16, 0, 0);
        }
    };

    // grid = 512, nchunks = 3125 -> T in {6,7} for every block.
    const int T = (nchunks - blockIdx.x + gridDim.x - 1) / gridDim.x;

    STAGE(0, blockIdx.x);
    STAGE(1, blockIdx.x + gridDim.x);
    STAGE(2, blockIdx.x + 2 * gridDim.x);

    for (int i = 0; i < T; ++i) {
        const int c  = blockIdx.x + i * gridDim.x;
        const bool st = (i + 3 < T);
        if (st) STAGE((i + 3) & 3, c + 3 * gridDim.x);

        // wait for chunk i's 4 staging loads: N = ops issued after them.
        if      (i == 0) asm volatile("s_waitcnt vmcnt(12)" ::: "memory");
        else if (i == 1) asm volatile("s_waitcnt vmcnt(20)" ::: "memory");
        else if (i == 2) asm volatile("s_waitcnt vmcnt(28)" ::: "memory");
        else if (st)     asm volatile("s_waitcnt vmcnt(36)" ::: "memory");
        else             asm volatile("s_waitcnt vmcnt(8)"  ::: "memory");
        __builtin_amdgcn_s_barrier();
        asm volatile("" ::: "memory");

        const uint32_t tb = lds0 + (uint32_t)((i & 3) * CHUNK_B);

        // --- 16 x ds_read_b128 via asm (keeps the LDS-DMA alias pass from
        // injecting vmcnt(0) here) ---
        f32x4 rf[2][4][2];
#pragma unroll
        for (int mt = 0; mt < 2; ++mt)
#pragma unroll
            for (int kk = 0; kk < 4; ++kk)
#pragma unroll
                for (int h = 0; h < 2; ++h) {
                    const int o = (mt * 16 + l15) * 512 + kk * 128 + q * 32 + h * 16;
                    asm volatile("ds_read_b128 %0, %1"
                                 : "=v"(rf[mt][kk][h])
                                 : "v"(tb + (uint32_t)swz(o)));
                }
        asm volatile("s_waitcnt lgkmcnt(0)" ::: "memory");
        __builtin_amdgcn_sched_barrier(0);     // rule #18: pin consumers below

        f32x4 acc[2][4];
#pragma unroll
        for (int mt = 0; mt < 2; ++mt)
#pragma unroll
            for (int nt = 0; nt < 4; ++nt)
                acc[mt][nt] = (f32x4){0.f, 0.f, 0.f, 0.f};

#pragma unroll
        for (int kk = 0; kk < 4; ++kk) {
            bfx8 af[2];
#pragma unroll
            for (int mt = 0; mt < 2; ++mt) {
                f32x4 f0 = rf[mt][kk][0], f1 = rf[mt][kk][1];
                bfx8 a;
                a[0]=(__bf16)f0[0]; a[1]=(__bf16)f0[1]; a[2]=(__bf16)f0[2]; a[3]=(__bf16)f0[3];
                a[4]=(__bf16)f1[0]; a[5]=(__bf16)f1[1]; a[6]=(__bf16)f1[2]; a[7]=(__bf16)f1[3];
                af[mt] = a;
            }
#pragma unroll
            for (int mt = 0; mt < 2; ++mt)
#pragma unroll
                for (int nt = 0; nt < 4; ++nt)
                    acc[mt][nt] = __builtin_amdgcn_mfma_f32_16x16x32_bf16(
                        bfrag[nt][kk], af[mt], acc[mt][nt], 0, 0, 0);
        }

        // --- direct epilogue: lane owns row m0+mt*16+l15, cols n0+nt*16+q*4..+4
        // (exactly 8 x 8B stores per wave -> the vmcnt N constants above) ---
        const int m0 = c * 32;
#pragma unroll
        for (int mt = 0; mt < 2; ++mt) {
            __bf16* dst = UV + (size_t)(m0 + mt * 16 + l15) * NCOL + n0 + q * 4;
#pragma unroll
            for (int nt = 0; nt < 4; ++nt) {
                bfx4 v;
#pragma unroll
                for (int r = 0; r < 4; ++r)
                    v[r] = (__bf16)(acc[mt][nt][r] + bias[nt][r]);
                *(bfx4*)(dst + nt * 16) = v;
            }
        }

        asm volatile("" ::: "memory");
        __builtin_amdgcn_s_barrier();
        asm volatile("" ::: "memory");
    }
}

// ---------------- per-edge MLP (R5 form: 2 edges / 16-lane group) ----------------
// R6: 2x gather-ILP neutral => bound by L2-miss fill (~141 MB @ ~3.4 TB/s),
// structural for random gathers over a 51 MB table.
__global__ __launch_bounds__(256) void edge_mlp(
    const __bf16* __restrict__ UV, const int* __restrict__ ei,
    const float* __restrict__ W2, const float* __restrict__ b2,
    float* __restrict__ out, int E)
{
    const int gt   = blockIdx.x * blockDim.x + threadIdx.x;
    const int lane = threadIdx.x & 15;
    const int g    = gt >> 4;
    const int e0   = g * 2;
    const int j0   = lane * 8;

    float ww[8];
    {
        float4 w0 = *(const float4*)(W2 + j0);
        float4 w1 = *(const float4*)(W2 + j0 + 4);
        ww[0] = w0.x; ww[1] = w0.y; ww[2] = w0.z; ww[3] = w0.w;
        ww[4] = w1.x; ww[5] = w1.y; ww[6] = w1.z; ww[7] = w1.w;
    }

    if (e0 >= E) return;   // E is even

    const int2 srcp = *(const int2*)(ei + e0);       // src of e0, e0+1
    const int2 dstp = *(const int2*)(ei + E + e0);   // dst of e0, e0+1

    bfx8 u0 = *(const bfx8*)(UV + (size_t)srcp.x * NCOL + j0);
    bfx8 v0 = *(const bfx8*)(UV + (size_t)dstp.x * NCOL + 128 + j0);
    bfx8 u1 = *(const bfx8*)(UV + (size_t)srcp.y * NCOL + j0);
    bfx8 v1 = *(const bfx8*)(UV + (size_t)dstp.y * NCOL + 128 + j0);

    float s0 = 0.f, s1 = 0.f;
#pragma unroll
    for (int i = 0; i < 8; ++i) {
        float h0 = (float)u0[i] + (float)v0[i];
        float h1 = (float)u1[i] + (float)v1[i];
        s0 = fmaf(fmaxf(h0, 0.f), ww[i], s0);
        s1 = fmaf(fmaxf(h1, 0.f), ww[i], s1);
    }

#pragma unroll
    for (int d = 1; d < 16; d <<= 1) {
        s0 += __shfl_xor(s0, d);
        s1 += __shfl_xor(s1, d);
    }

    if (lane == 0) {
        float bb = b2[0];
        *(float2*)(out + e0) = make_float2(s0 + bb, s1 + bb);
    }
}

extern "C" void kernel_launch(void* const* d_in, const int* in_sizes, int n_in,
                              void* d_out, int out_size, void* d_ws, size_t ws_size,
                              hipStream_t stream)
{
    const float* z  = (const float*)d_in[0];
    const int*   ei = (const int*)d_in[1];
    const float* W1 = (const float*)d_in[2];
    const float* b1 = (const float*)d_in[3];
    const float* W2 = (const float*)d_in[4];
    const float* b2 = (const float*)d_in[5];
    float* out = (float*)d_out;

    const int M = in_sizes[0] / IN_DIM;   // 100000 nodes
    const int E = in_sizes[1] / 2;        // 600000 edges

    __bf16* UV   = (__bf16*)d_ws;                    // [M][256] bf16 = 51.2 MB
    __bf16* Weff = UV + (size_t)M * NCOL;            // [256][128] bf16 = 64 KB

    prep_w<<<1, 256, 0, stream>>>(W1, Weff);

    const int nchunks = M / 32;           // 3125 (M % 32 == 0)
    gemm_mfma<<<512, 256, 0, stream>>>(z, Weff, b1, UV, nchunks);

    int groups  = (E + 1) / 2;            // 2 edges per 16-lane group
    int eblocks = (groups * 16 + 255) / 256;  // 18750
    edge_mlp<<<eblocks, 256, 0, stream>>>(UV, ei, W2, b2, out, E);
}

// Round 12
// 147.725 us; speedup vs baseline: 1.1017x; 1.0643x over previous
//
#include <hip/hip_runtime.h>
#include <stdint.h>

#define IN_DIM 128
#define NCOL   256   // UV row: [U(128) | V(128)], bf16
#define CHUNK_B (32 * IN_DIM * 4)   // one A-chunk in LDS: 16 KB

typedef __bf16 bfx8 __attribute__((ext_vector_type(8)));
typedef __bf16 bfx4 __attribute__((ext_vector_type(4)));
typedef float  f32x4 __attribute__((ext_vector_type(4)));
typedef __attribute__((address_space(3))) void lds_void;

// XOR-swizzle on chunk-local byte offsets (16 KB = 32 rows x 512 B) for the
// A-tile staging/read path. Involution; keeps 16B alignment; applied on BOTH
// sides (pre-swizzled global source + swizzled ds_read).
__device__ __forceinline__ int swz(int x) { return x ^ (((x >> 9) & 7) << 4); }

// ---------------- GEMM: UV = bf16( z @ Weff^T + [b1|0] ) ----------------
// Base = exact R8 (best measured, 151.5 total): 4-buffer LDS ring, prefetch
// depth 3, raw s_barrier + counted s_waitcnt vmcnt(N), grid 512 (T in {6,7}).
// R12 change: LDS-transposed epilogue. The register-direct bfx4 stores
// scattered 64x8B over 16 rows -> 32B partial-line segments, 4x the L2 write
// transactions (the last unexamined cost; reads are clean, WRITE=50MB exact).
// Now: C-tile (16 KB) -> just-consumed ring buffer (safe: its next staging
// write is iter i+1's STAGE, issued only after barrier2), then 4 coalesced
// dwordx4 stores/thread (1 KB contiguous per wave-instr, full lines).
// vmcnt accounting with 4 stores/iter: after STAGE(i) the ops are
// stores(i-3)=4, stage(i+1)+stores(i-2)=8, stage(i+2)+stores(i-1)=8,
// stage(i+3)=4 => steady N=24; warmup 12/16/20; tail 12 (over-wait safe).
// All epilogue LDS ops are inline asm (the LDS-DMA alias pass would inject
// vmcnt(0) before compiler-emitted ds ops touching abuf).
__global__ __launch_bounds__(256, 2) void gemm_mfma(
    const float* __restrict__ z, const float* __restrict__ W1,
    const float* __restrict__ b1, __bf16* __restrict__ UV, int nchunks)
{
    __shared__ float abuf[4][32 * IN_DIM];   // 4 x 16 KB ring

    const int tid  = threadIdx.x;
    const int wave = tid >> 6;
    const int lane = tid & 63;
    const int l15  = lane & 15;
    const int q    = lane >> 4;      // quad 0..3
    const int n0   = wave * 64;

    // --- B fragments from W1 f32 (L2/L3-hot), fused concat:
    // Weff[n][k] = (n<128) ? W1[n][k] : W1[n-128][128+k]
    bfx8  bfrag[4][4];
    f32x4 bias[4];
#pragma unroll
    for (int nt = 0; nt < 4; ++nt) {
        const int n = n0 + nt * 16 + l15;
        const float* src = (n < 128) ? (W1 + (size_t)n * 256)
                                     : (W1 + (size_t)(n - 128) * 256 + 128);
#pragma unroll
        for (int kk = 0; kk < 4; ++kk) {
            float4 f0 = *(const float4*)(src + kk * 32 + q * 8);
            float4 f1 = *(const float4*)(src + kk * 32 + q * 8 + 4);
            bfx8 b;
            b[0]=(__bf16)f0.x; b[1]=(__bf16)f0.y; b[2]=(__bf16)f0.z; b[3]=(__bf16)f0.w;
            b[4]=(__bf16)f1.x; b[5]=(__bf16)f1.y; b[6]=(__bf16)f1.z; b[7]=(__bf16)f1.w;
            bfrag[nt][kk] = b;
        }
        if (n0 + nt * 16 < 128) bias[nt] = *(const f32x4*)(b1 + n0 + nt * 16 + q * 4);
        else                    bias[nt] = (f32x4){0.f, 0.f, 0.f, 0.f};
    }

    const uint32_t lds0 = (uint32_t)(uintptr_t)(lds_void*)&abuf[0][0];

    auto STAGE = [&](int b, int cc) {
        const char* gbase = (const char*)(z + (size_t)cc * 32 * IN_DIM);
#pragma unroll
        for (int i = 0; i < 4; ++i) {
            const int seg  = (wave * 4 + i) << 10;   // 1 KB per wave-instr
            const int loff = seg + lane * 16;
            __builtin_amdgcn_global_load_lds(
                (const __attribute__((address_space(1))) void*)(gbase + swz(loff)),
                (lds_void*)((char*)&abuf[b][0] + seg),
                16, 0, 0);
        }
    };

    // grid = 512, nchunks = 3125 -> T in {6,7} for every block (T>=6 needed
    // by the warmup constants).
    const int T = (nchunks - blockIdx.x + gridDim.x - 1) / gridDim.x;

    STAGE(0, blockIdx.x);
    STAGE(1, blockIdx.x + gridDim.x);
    STAGE(2, blockIdx.x + 2 * gridDim.x);

    for (int i = 0; i < T; ++i) {
        const int c  = blockIdx.x + i * gridDim.x;
        const bool st = (i + 3 < T);
        if (st) STAGE((i + 3) & 3, c + 3 * gridDim.x);

        // wait for chunk i's 4 staging loads: N = ops issued after them.
        if      (i == 0) asm volatile("s_waitcnt vmcnt(12)" ::: "memory");
        else if (i == 1) asm volatile("s_waitcnt vmcnt(16)" ::: "memory");
        else if (i == 2) asm volatile("s_waitcnt vmcnt(20)" ::: "memory");
        else if (st)     asm volatile("s_waitcnt vmcnt(24)" ::: "memory");
        else             asm volatile("s_waitcnt vmcnt(12)" ::: "memory");
        __builtin_amdgcn_s_barrier();          // chunk i staged for all waves
        asm volatile("" ::: "memory");

        const uint32_t tb = lds0 + (uint32_t)((i & 3) * CHUNK_B);

        // --- 16 x ds_read_b128 via asm ---
        f32x4 rf[2][4][2];
#pragma unroll
        for (int mt = 0; mt < 2; ++mt)
#pragma unroll
            for (int kk = 0; kk < 4; ++kk)
#pragma unroll
                for (int h = 0; h < 2; ++h) {
                    const int o = (mt * 16 + l15) * 512 + kk * 128 + q * 32 + h * 16;
                    asm volatile("ds_read_b128 %0, %1"
                                 : "=v"(rf[mt][kk][h])
                                 : "v"(tb + (uint32_t)swz(o)));
                }
        asm volatile("s_waitcnt lgkmcnt(0)" ::: "memory");
        __builtin_amdgcn_sched_barrier(0);     // rule #18: pin consumers below

        f32x4 acc[2][4];
#pragma unroll
        for (int mt = 0; mt < 2; ++mt)
#pragma unroll
            for (int nt = 0; nt < 4; ++nt)
                acc[mt][nt] = (f32x4){0.f, 0.f, 0.f, 0.f};

#pragma unroll
        for (int kk = 0; kk < 4; ++kk) {
            bfx8 af[2];
#pragma unroll
            for (int mt = 0; mt < 2; ++mt) {
                f32x4 f0 = rf[mt][kk][0], f1 = rf[mt][kk][1];
                bfx8 a;
                a[0]=(__bf16)f0[0]; a[1]=(__bf16)f0[1]; a[2]=(__bf16)f0[2]; a[3]=(__bf16)f0[3];
                a[4]=(__bf16)f1[0]; a[5]=(__bf16)f1[1]; a[6]=(__bf16)f1[2]; a[7]=(__bf16)f1[3];
                af[mt] = a;
            }
#pragma unroll
            for (int mt = 0; mt < 2; ++mt)
#pragma unroll
                for (int nt = 0; nt < 4; ++nt)
                    acc[mt][nt] = __builtin_amdgcn_mfma_f32_16x16x32_bf16(
                        bfrag[nt][kk], af[mt], acc[mt][nt], 0, 0, 0);
        }

        // ---- LDS-transposed epilogue ----
        // barrier: all waves' A-reads of buf i&3 done -> safe to overwrite.
        asm volatile("" ::: "memory");
        __builtin_amdgcn_s_barrier();
        asm volatile("" ::: "memory");

        // C-tile 32x256 bf16, row-major 512 B/row, bank-swizzle ^((row&7)<<4).
        // Lane writes bfx4 (8B) at row mt*16+l15, col n0+nt*16+q*4.
#pragma unroll
        for (int mt = 0; mt < 2; ++mt) {
            const int row = mt * 16 + l15;
            const uint32_t rb = tb + (uint32_t)(row * 512);
            const uint32_t sx = (uint32_t)((row & 7) << 4);
#pragma unroll
            for (int nt = 0; nt < 4; ++nt) {
                bfx4 v;
#pragma unroll
                for (int r = 0; r < 4; ++r)
                    v[r] = (__bf16)(acc[mt][nt][r] + bias[nt][r]);
                const uint32_t a = rb + ((uint32_t)((n0 + nt * 16 + q * 4) * 2) ^ sx);
                asm volatile("ds_write_b64 %0, %1" :: "v"(a), "v"(v));
            }
        }
        asm volatile("s_waitcnt lgkmcnt(0)" ::: "memory");
        __builtin_amdgcn_s_barrier();          // C-tile visible to all waves
        asm volatile("" ::: "memory");

        // coalesced store: 1024 dwordx4 pieces; thread takes s*256+tid ->
        // per wave-instr 64 x 16 B contiguous = 1 KB, full 128 B lines.
        const int m0 = c * 32;
        bfx8 cv[4];
#pragma unroll
        for (int s = 0; s < 4; ++s) {
            const int lin = s * 256 + tid;
            const int row = lin >> 5;
            const uint32_t a = tb +
                ((uint32_t)(row * 512 + (lin & 31) * 16) ^ (uint32_t)((row & 7) << 4));
            asm volatile("ds_read_b128 %0, %1" : "=v"(cv[s]) : "v"(a));
        }
        asm volatile("s_waitcnt lgkmcnt(0)" ::: "memory");
        __builtin_amdgcn_sched_barrier(0);
#pragma unroll
        for (int s = 0; s < 4; ++s) {
            const int lin = s * 256 + tid;
            const int row = lin >> 5;
            *(bfx8*)(UV + (size_t)(m0 + row) * NCOL + (lin & 31) * 8) = cv[s];
        }

        asm volatile("" ::: "memory");
        __builtin_amdgcn_s_barrier();          // epilogue LDS reads done before
        asm volatile("" ::: "memory");         // iter i+1's STAGE rewrites buf i&3
    }
}

// ---------------- per-edge MLP (R5 form: 2 edges / 16-lane group) ----------------
// R6: 2x gather-ILP neutral => bound by L2-miss fill (~141 MB @ ~3.4 TB/s),
// structural for random gathers over a 51 MB table.
__global__ __launch_bounds__(256) void edge_mlp(
    const __bf16* __restrict__ UV, const int* __restrict__ ei,
    const float* __restrict__ W2, const float* __restrict__ b2,
    float* __restrict__ out, int E)
{
    const int gt   = blockIdx.x * blockDim.x + threadIdx.x;
    const int lane = threadIdx.x & 15;
    const int g    = gt >> 4;
    const int e0   = g * 2;
    const int j0   = lane * 8;

    float ww[8];
    {
        float4 w0 = *(const float4*)(W2 + j0);
        float4 w1 = *(const float4*)(W2 + j0 + 4);
        ww[0] = w0.x; ww[1] = w0.y; ww[2] = w0.z; ww[3] = w0.w;
        ww[4] = w1.x; ww[5] = w1.y; ww[6] = w1.z; ww[7] = w1.w;
    }

    if (e0 >= E) return;   // E is even

    const int2 srcp = *(const int2*)(ei + e0);       // src of e0, e0+1
    const int2 dstp = *(const int2*)(ei + E + e0);   // dst of e0, e0+1

    bfx8 u0 = *(const bfx8*)(UV + (size_t)srcp.x * NCOL + j0);
    bfx8 v0 = *(const bfx8*)(UV + (size_t)dstp.x * NCOL + 128 + j0);
    bfx8 u1 = *(const bfx8*)(UV + (size_t)srcp.y * NCOL + j0);
    bfx8 v1 = *(const bfx8*)(UV + (size_t)dstp.y * NCOL + 128 + j0);

    float s0 = 0.f, s1 = 0.f;
#pragma unroll
    for (int i = 0; i < 8; ++i) {
        float h0 = (float)u0[i] + (float)v0[i];
        float h1 = (float)u1[i] + (float)v1[i];
        s0 = fmaf(fmaxf(h0, 0.f), ww[i], s0);
        s1 = fmaf(fmaxf(h1, 0.f), ww[i], s1);
    }

#pragma unroll
    for (int d = 1; d < 16; d <<= 1) {
        s0 += __shfl_xor(s0, d);
        s1 += __shfl_xor(s1, d);
    }

    if (lane == 0) {
        float bb = b2[0];
        *(float2*)(out + e0) = make_float2(s0 + bb, s1 + bb);
    }
}

extern "C" void kernel_launch(void* const* d_in, const int* in_sizes, int n_in,
                              void* d_out, int out_size, void* d_ws, size_t ws_size,
                              hipStream_t stream)
{
    const float* z  = (const float*)d_in[0];
    const int*   ei = (const int*)d_in[1];
    const float* W1 = (const float*)d_in[2];
    const float* b1 = (const float*)d_in[3];
    const float* W2 = (const float*)d_in[4];
    const float* b2 = (const float*)d_in[5];
    float* out = (float*)d_out;

    const int M = in_sizes[0] / IN_DIM;   // 100000 nodes
    const int E = in_sizes[1] / 2;        // 600000 edges

    __bf16* UV = (__bf16*)d_ws;           // [M][256] bf16 = 51.2 MB

    const int nchunks = M / 32;           // 3125 (M % 32 == 0)
    gemm_mfma<<<512, 256, 0, stream>>>(z, W1, b1, UV, nchunks);

    int groups  = (E + 1) / 2;            // 2 edges per 16-lane group
    int eblocks = (groups * 16 + 255) / 256;  // 18750
    edge_mlp<<<eblocks, 256, 0, stream>>>(UV, ei, W2, b2, out, E);
}